// Round 8
// baseline (247.200 us; speedup 1.0000x reference)
//
#include <hip/hip_runtime.h>
#include <hip/hip_fp16.h>
#include <cstdint>
#include <cstddef>

// SlotAttention, round 7.
//  - xh_prep: streaming LN -> fp16 (wave-per-row, no LDS, no syncs).
//  - fused_attn_f16: 32-token chunks, all 3 iterations; dots = xh.qk + qkb.
//  - slot_update: 1024-thread k-split chain, fp16 weights (round-6 proven),
//    NCHK=128; qkb-only tail (C0/G machinery removed).

#define NTOK 4096
#define DDIM 256
#define NSLOT 8
#define NBATCH 32
#define CH 32                    // tokens per fused block
#define NCHK 128                 // chunks per batch
#define SROWS (NBATCH * NSLOT)
#define NROWS (NBATCH * NTOK)
#define SCALE 0.0625f
#define LN_EPS_C 1e-5f
#define ATTN_EPS_C 1e-8f

__device__ __forceinline__ void wave_reduce2(float& s, float& ss) {
#pragma unroll
  for (int off = 32; off > 0; off >>= 1) {
    s  += __shfl_down(s, off, 64);
    ss += __shfl_down(ss, off, 64);
  }
}
__device__ __forceinline__ void wave_reduce2_xor(float& s, float& ss) {
#pragma unroll
  for (int off = 32; off > 0; off >>= 1) {
    s  += __shfl_xor(s, off, 64);
    ss += __shfl_xor(ss, off, 64);
  }
}

// transpose 6 weight matrices to fp16; plain-convert Wk to fp16 (r6 proven).
__global__ __launch_bounds__(256) void convert_weights_k(
    const float* __restrict__ Wq, const float* __restrict__ Wv,
    const float* __restrict__ Wih, const float* __restrict__ Whh,
    const float* __restrict__ W1, const float* __restrict__ W2,
    const float* __restrict__ Wk, __half* __restrict__ WqT,
    __half* __restrict__ WvT, __half* __restrict__ WihT,
    __half* __restrict__ WhhT, __half* __restrict__ W1T,
    __half* __restrict__ W2T, __half* __restrict__ Wk_h) {
  __shared__ float tile[32][33];
  int bz = blockIdx.x;
  int tx = threadIdx.x & 31, ty = threadIdx.x >> 5;
  if (bz >= 80) {
    int ro = (bz - 80) * 32, cd = blockIdx.y * 32;
#pragma unroll
    for (int p = 0; p < 32; p += 8)
      Wk_h[(size_t)(ro + ty + p) * DDIM + cd + tx] =
          __float2half(Wk[(size_t)(ro + ty + p) * DDIM + cd + tx]);
    return;
  }
  const float* in; __half* out; int O, bo;
  if (bz < 8)       { in = Wq;  out = WqT;  O = 256; bo = bz; }
  else if (bz < 16) { in = Wv;  out = WvT;  O = 256; bo = bz - 8; }
  else if (bz < 40) { in = Wih; out = WihT; O = 768; bo = bz - 16; }
  else if (bz < 64) { in = Whh; out = WhhT; O = 768; bo = bz - 40; }
  else if (bz < 72) { in = W1;  out = W1T;  O = 256; bo = bz - 64; }
  else              { in = W2;  out = W2T;  O = 256; bo = bz - 72; }
  int ro = bo * 32, cd = blockIdx.y * 32;
#pragma unroll
  for (int p = 0; p < 32; p += 8)
    tile[ty + p][tx] = in[(size_t)(ro + ty + p) * DDIM + cd + tx];
  __syncthreads();
#pragma unroll
  for (int p = 0; p < 32; p += 8)
    out[(size_t)(cd + ty + p) * O + ro + tx] = __float2half(tile[tx][ty + p]);
}

// streaming LN -> fp16. wave per row (64 lanes x float4 = 256 floats).
__global__ __launch_bounds__(256) void xh_prep_k(
    const float* __restrict__ X, const float* __restrict__ g,
    const float* __restrict__ be, __half* __restrict__ xh) {
  int row = blockIdx.x * 4 + (threadIdx.x >> 6);
  int lane = threadIdx.x & 63;
  float4 a = *(const float4*)(X + (size_t)row * DDIM + lane * 4);
  float s = a.x + a.y + a.z + a.w;
  float ss = a.x * a.x + a.y * a.y + a.z * a.z + a.w * a.w;
  wave_reduce2_xor(s, ss);
  float m = s * (1.f / DDIM);
  float rs = rsqrtf(ss * (1.f / DDIM) - m * m + LN_EPS_C);
  float4 gv = *(const float4*)(g + lane * 4);
  float4 bev = *(const float4*)(be + lane * 4);
  union { __half2 h[2]; uint2 u; } pk;
  pk.h[0] = __floats2half2_rn((a.x - m) * rs * gv.x + bev.x,
                              (a.y - m) * rs * gv.y + bev.y);
  pk.h[1] = __floats2half2_rn((a.z - m) * rs * gv.z + bev.z,
                              (a.w - m) * rs * gv.w + bev.w);
  *(uint2*)(xh + (size_t)row * DDIM + lane * 4) = pk.u;
}

// per-iteration token pass: block = (b, 32-token chunk c), 256 threads.
//  stage xh tile -> LDS (stride 258 halves: conflict-audited)
//  A (tj=t&31 token, qd=t>>5 dim-slice of 32): p[8] partials; shfl pair-reduce
//  B (t<32): dots = sum part + qkb; softmax; sa; S partial
//  C (thread=dim): u accumulation -> fp16 plain store
__global__ __launch_bounds__(256) void fused_attn_f16_k(
    const __half* __restrict__ xh, const float* __restrict__ qk,
    const float* __restrict__ qkb, float* __restrict__ attn_out,
    float* __restrict__ S_part, __half* __restrict__ u_part, int write_attn) {
  __shared__ __half sx[CH][258];       // 516B rows: 129 dwords = 1 mod 32
  __shared__ float2 sqkf[NSLOT][128];
  __shared__ float part[4][NSLOT][CH];
  __shared__ float sa[NSLOT][CH];
  __shared__ float sC0[NSLOT], sS[NSLOT];
  int b = blockIdx.x, c = blockIdx.y, t = threadIdx.x;
  {
    int i = t >> 5, p2 = t & 31;
    const float* qr = qk + ((size_t)b * NSLOT + i) * DDIM;
#pragma unroll
    for (int kk = 0; kk < 4; ++kk) {
      int col = p2 * 4 + kk;
      sqkf[i][col] = make_float2(qr[col * 2], qr[col * 2 + 1]);
    }
  }
  if (t < NSLOT) sC0[t] = qkb[b * NSLOT + t];
  const size_t base = (size_t)b * NTOK + (size_t)c * CH;
#pragma unroll
  for (int it = 0; it < 4; ++it) {
    int e = it * 256 + t;
    int row = e >> 5, c16 = e & 31;
    uint4 v = *(const uint4*)(xh + (base + row) * DDIM + c16 * 8);
    __half2* dst = (__half2*)&sx[row][c16 * 8];
    dst[0] = ((const __half2*)&v)[0];
    dst[1] = ((const __half2*)&v)[1];
    dst[2] = ((const __half2*)&v)[2];
    dst[3] = ((const __half2*)&v)[3];
  }
  __syncthreads();
  // phase A
  int tj = t & 31, qd = t >> 5;
  float p[NSLOT] = {};
  const __half2* xrow = (const __half2*)&sx[tj][qd * 32];
#pragma unroll
  for (int dd2 = 0; dd2 < 16; ++dd2) {
    float2 xf = __half22float2(xrow[dd2]);
#pragma unroll
    for (int i = 0; i < NSLOT; ++i) {
      float2 qf = sqkf[i][qd * 16 + dd2];
      p[i] = fmaf(xf.x, qf.x, fmaf(xf.y, qf.y, p[i]));
    }
  }
#pragma unroll
  for (int i = 0; i < NSLOT; ++i) p[i] += __shfl_down(p[i], 32, 64);
  int w = t >> 6;
  if ((t & 63) < 32) {
#pragma unroll
    for (int i = 0; i < NSLOT; ++i) part[w][i][tj] = p[i];
  }
  __syncthreads();
  // phase B
  if (t < CH) {
    float dots[NSLOT], mx = -1e30f;
#pragma unroll
    for (int i = 0; i < NSLOT; ++i) {
      dots[i] = part[0][i][t] + part[1][i][t] + part[2][i][t] +
                part[3][i][t] + sC0[i];
      mx = fmaxf(mx, dots[i]);
    }
    float sum = 0.f;
#pragma unroll
    for (int i = 0; i < NSLOT; ++i) { dots[i] = expf(dots[i] - mx); sum += dots[i]; }
    float inv = 1.f / sum;
#pragma unroll
    for (int i = 0; i < NSLOT; ++i) {
      float a = dots[i] * inv;
      if (write_attn)
        attn_out[((size_t)b * NSLOT + i) * NTOK + c * CH + t] = a;
      float ae = a + ATTN_EPS_C;
      sa[i][t] = ae;
      float ps = ae;
#pragma unroll
      for (int off = 16; off > 0; off >>= 1) ps += __shfl_down(ps, off, 32);
      if (t == 0) sS[i] = ps;
    }
  }
  __syncthreads();
  // phase C
  float acc[NSLOT] = {};
#pragma unroll
  for (int jj = 0; jj < CH; ++jj) {
    float x = __half2float(sx[jj][t]);
#pragma unroll
    for (int i = 0; i < NSLOT; ++i) acc[i] = fmaf(x, sa[i][jj], acc[i]);
  }
  __half* upb = u_part + (((size_t)b * NCHK + c) * NSLOT) * DDIM + t;
#pragma unroll
  for (int i = 0; i < NSLOT; ++i) upb[(size_t)i * DDIM] = __float2half(acc[i]);
  if (t < NSLOT) S_part[((size_t)b * NCHK + c) * NSLOT + t] = sS[t];
}

// slot path, 1024 threads: o = t&255, ks = t>>8. fp16 weights.
__global__ __launch_bounds__(1024) void slot_update_k(
    const __half* __restrict__ u_part, const float* __restrict__ S_part,
    const float* __restrict__ slots_in, const __half* __restrict__ WvT,
    const float* __restrict__ bv, const __half* __restrict__ WihT,
    const __half* __restrict__ WhhT, const float* __restrict__ b_ih,
    const float* __restrict__ b_hh, const float* __restrict__ g_ff,
    const float* __restrict__ be_ff, const __half* __restrict__ W1T,
    const float* __restrict__ b1, const __half* __restrict__ W2T,
    const float* __restrict__ b2, const float* __restrict__ g_sl,
    const float* __restrict__ be_sl, const __half* __restrict__ WqT,
    const float* __restrict__ bq, const __half* __restrict__ Wk_h,
    const float* __restrict__ bk, const float* __restrict__ noise,
    const float* __restrict__ mu, const float* __restrict__ logsig,
    float* __restrict__ slots_out, float* __restrict__ qk,
    float* __restrict__ qkb_out, int init, int compute_qk) {
  __shared__ float red[4][6][DDIM];
  __shared__ float su[DDIM], sh[DDIM], supd[DDIM], v1[DDIM], v2[DDIM];
  __shared__ float scal[16];
  int r = blockIdx.x, t = threadIdx.x;
  int b = r >> 3, i = r & 7;
  int o = t & 255, ks = t >> 8;
  int lane = t & 63, wid = t >> 6;
  if (init) {
    if (ks == 0) {
      float ns = mu[o] + expf(logsig[o]) * noise[(size_t)r * DDIM + o];
      slots_out[(size_t)r * DDIM + o] = ns;
      v2[o] = ns;
    }
    __syncthreads();
  } else {
    // phase 0: u partials + S reduce + h load
    {
      float up = 0.f;
      const __half* upp =
          u_part + (((size_t)b * NCHK + ks * 32) * NSLOT + i) * DDIM + o;
#pragma unroll
      for (int cc = 0; cc < 32; ++cc)
        up += __half2float(upp[(size_t)cc * (NSLOT * DDIM)]);
      red[ks][0][o] = up;
    }
    if (t < 128) {
      float sp = S_part[((size_t)b * NCHK + t) * NSLOT + i];
#pragma unroll
      for (int off = 32; off > 0; off >>= 1) sp += __shfl_down(sp, off, 64);
      if ((t & 63) == 0) scal[12 + (t >> 6)] = sp;
    }
    if (ks == 0) sh[o] = slots_in[(size_t)r * DDIM + o];
    __syncthreads();
    if (ks == 0) {
      float invS = 1.f / (scal[12] + scal[13]);
      su[o] = (red[0][0][o] + red[1][0][o] + red[2][0][o] + red[3][0][o]) * invS;
    }
    __syncthreads();
    // phase 1: Wv
    {
      float p = 0.f;
      const __half* wp = WvT + (size_t)(ks * 64) * DDIM + o;
#pragma unroll 8
      for (int dd = 0; dd < 64; ++dd)
        p = fmaf(su[ks * 64 + dd], __half2float(wp[(size_t)dd * DDIM]), p);
      red[ks][0][o] = p;
    }
    __syncthreads();
    if (ks == 0)
      supd[o] = bv[o] + red[0][0][o] + red[1][0][o] + red[2][0][o] + red[3][0][o];
    __syncthreads();
    // phase 2: GRU (6 matvecs)
    {
      float p0 = 0, p1 = 0, p2 = 0, p3 = 0, p4 = 0, p5 = 0;
      const __half* pi = WihT + (size_t)(ks * 64) * (3 * DDIM) + o;
      const __half* ph = WhhT + (size_t)(ks * 64) * (3 * DDIM) + o;
#pragma unroll 4
      for (int dd = 0; dd < 64; ++dd) {
        float ud = supd[ks * 64 + dd], hd = sh[ks * 64 + dd];
        size_t off = (size_t)dd * (3 * DDIM);
        p0 = fmaf(ud, __half2float(pi[off]), p0);
        p1 = fmaf(ud, __half2float(pi[off + DDIM]), p1);
        p2 = fmaf(ud, __half2float(pi[off + 2 * DDIM]), p2);
        p3 = fmaf(hd, __half2float(ph[off]), p3);
        p4 = fmaf(hd, __half2float(ph[off + DDIM]), p4);
        p5 = fmaf(hd, __half2float(ph[off + 2 * DDIM]), p5);
      }
      red[ks][0][o] = p0; red[ks][1][o] = p1; red[ks][2][o] = p2;
      red[ks][3][o] = p3; red[ks][4][o] = p4; red[ks][5][o] = p5;
    }
    __syncthreads();
    if (ks == 0) {
      float air = b_ih[o] + red[0][0][o] + red[1][0][o] + red[2][0][o] + red[3][0][o];
      float aiz = b_ih[DDIM + o] + red[0][1][o] + red[1][1][o] + red[2][1][o] + red[3][1][o];
      float ain = b_ih[2 * DDIM + o] + red[0][2][o] + red[1][2][o] + red[2][2][o] + red[3][2][o];
      float ahr = b_hh[o] + red[0][3][o] + red[1][3][o] + red[2][3][o] + red[3][3][o];
      float ahz = b_hh[DDIM + o] + red[0][4][o] + red[1][4][o] + red[2][4][o] + red[3][4][o];
      float ahn = b_hh[2 * DDIM + o] + red[0][5][o] + red[1][5][o] + red[2][5][o] + red[3][5][o];
      float rg = 1.f / (1.f + expf(-(air + ahr)));
      float zg = 1.f / (1.f + expf(-(aiz + ahz)));
      float ng = tanhf(ain + rg * ahn);
      float nh = (1.f - zg) * ng + zg * sh[o];
      v1[o] = nh;
      float s2 = nh, ss2 = nh * nh;
      wave_reduce2(s2, ss2);
      if (lane == 0) { scal[wid] = s2; scal[4 + wid] = ss2; }
    }
    __syncthreads();
    if (ks == 0) {
      float sS = scal[0] + scal[1] + scal[2] + scal[3];
      float sQ = scal[4] + scal[5] + scal[6] + scal[7];
      float m = sS * (1.f / DDIM);
      float rs = rsqrtf(sQ * (1.f / DDIM) - m * m + LN_EPS_C);
      v2[o] = (v1[o] - m) * rs * g_ff[o] + be_ff[o];
    }
    __syncthreads();
    // phase 3: W1 + relu
    {
      float p = 0.f;
      const __half* wp = W1T + (size_t)(ks * 64) * DDIM + o;
#pragma unroll 8
      for (int dd = 0; dd < 64; ++dd)
        p = fmaf(v2[ks * 64 + dd], __half2float(wp[(size_t)dd * DDIM]), p);
      red[ks][0][o] = p;
    }
    __syncthreads();
    if (ks == 0)
      su[o] = fmaxf(b1[o] + red[0][0][o] + red[1][0][o] + red[2][0][o] + red[3][0][o], 0.f);
    __syncthreads();
    // phase 4: W2 + residual
    {
      float p = 0.f;
      const __half* wp = W2T + (size_t)(ks * 64) * DDIM + o;
#pragma unroll 8
      for (int dd = 0; dd < 64; ++dd)
        p = fmaf(su[ks * 64 + dd], __half2float(wp[(size_t)dd * DDIM]), p);
      red[ks][0][o] = p;
    }
    __syncthreads();
    if (ks == 0) {
      float out = v1[o] + b2[o] + red[0][0][o] + red[1][0][o] + red[2][0][o] + red[3][0][o];
      slots_out[(size_t)r * DDIM + o] = out;
      v2[o] = out;
    }
    __syncthreads();
  }
  if (!compute_qk) return;
  // qk tail: LN(v2) -> q -> qk, qkb
  if (ks == 0) {
    float x = v2[o];
    float s2 = x, ss2 = x * x;
    wave_reduce2(s2, ss2);
    if (lane == 0) { scal[wid] = s2; scal[4 + wid] = ss2; }
  }
  __syncthreads();
  if (ks == 0) {
    float sS = scal[0] + scal[1] + scal[2] + scal[3];
    float sQ = scal[4] + scal[5] + scal[6] + scal[7];
    float m = sS * (1.f / DDIM);
    float rs = rsqrtf(sQ * (1.f / DDIM) - m * m + LN_EPS_C);
    su[o] = (v2[o] - m) * rs * g_sl[o] + be_sl[o];
  }
  __syncthreads();
  {
    float p = 0.f;
    const __half* wp = WqT + (size_t)(ks * 64) * DDIM + o;
#pragma unroll 8
    for (int dd = 0; dd < 64; ++dd)
      p = fmaf(su[ks * 64 + dd], __half2float(wp[(size_t)dd * DDIM]), p);
    red[ks][0][o] = p;
  }
  __syncthreads();
  if (ks == 0)
    sh[o] = bq[o] + red[0][0][o] + red[1][0][o] + red[2][0][o] + red[3][0][o];
  __syncthreads();
  {
    float p = 0.f;
    const __half* wp = Wk_h + (size_t)(ks * 64) * DDIM + o;
#pragma unroll 8
    for (int dd = 0; dd < 64; ++dd)
      p = fmaf(sh[ks * 64 + dd], __half2float(wp[(size_t)dd * DDIM]), p);
    red[ks][0][o] = p;
  }
  __syncthreads();
  if (ks == 0) {
    float qkv = SCALE * (red[0][0][o] + red[1][0][o] + red[2][0][o] + red[3][0][o]);
    qk[(size_t)r * DDIM + o] = qkv;
    float v0 = sh[o] * bk[o], d1 = 0.f;
    wave_reduce2(v0, d1);
    if (lane == 0) scal[wid] = v0;
  }
  __syncthreads();
  if (t == 0)
    qkb_out[r] = SCALE * (scal[0] + scal[1] + scal[2] + scal[3]);
}

extern "C" void kernel_launch(void* const* d_in, const int* in_sizes, int n_in,
                              void* d_out, int out_size, void* d_ws,
                              size_t ws_size, hipStream_t stream) {
  const float* inputs   = (const float*)d_in[0];
  const float* noise    = (const float*)d_in[1];
  const float* slots_mu = (const float*)d_in[2];
  const float* slots_ls = (const float*)d_in[3];
  const float* Wq   = (const float*)d_in[4];
  const float* bq   = (const float*)d_in[5];
  const float* Wk   = (const float*)d_in[6];
  const float* bk   = (const float*)d_in[7];
  const float* Wv   = (const float*)d_in[8];
  const float* bv   = (const float*)d_in[9];
  const float* W_ih = (const float*)d_in[10];
  const float* W_hh = (const float*)d_in[11];
  const float* b_ih = (const float*)d_in[12];
  const float* b_hh = (const float*)d_in[13];
  const float* W1   = (const float*)d_in[14];
  const float* b1   = (const float*)d_in[15];
  const float* W2   = (const float*)d_in[16];
  const float* b2   = (const float*)d_in[17];
  const float* g_in = (const float*)d_in[18];
  const float* be_in= (const float*)d_in[19];
  const float* g_sl = (const float*)d_in[20];
  const float* be_sl= (const float*)d_in[21];
  const float* g_ff = (const float*)d_in[22];
  const float* be_ff= (const float*)d_in[23];

  float* out_slots = (float*)d_out;                 // [32,8,256]
  float* out_attn  = (float*)d_out + SROWS * DDIM;  // [32,8,4096]

  float* w = (float*)d_ws;
  float* slots = w;  w += SROWS * DDIM;
  float* qk = w;     w += SROWS * DDIM;
  float* qkb = w;    w += SROWS;
  float* S_part = w; w += NBATCH * NCHK * NSLOT;   // 32768
  __half* h = (__half*)w;
  __half* xh = h;     h += (size_t)NROWS * DDIM;                  // 67 MB
  __half* u_part = h; h += (size_t)NBATCH * NCHK * NSLOT * DDIM;  // 16.8 MB
  __half* WqT_h = h;  h += DDIM * DDIM;
  __half* WvT_h = h;  h += DDIM * DDIM;
  __half* WihT_h = h; h += DDIM * 3 * DDIM;
  __half* WhhT_h = h; h += DDIM * 3 * DDIM;
  __half* W1T_h = h;  h += DDIM * DDIM;
  __half* W2T_h = h;  h += DDIM * DDIM;
  __half* Wk_h = h;   h += DDIM * DDIM;
  // total ws ~ 90 MB (ws ~512 MB per harness fill)

  convert_weights_k<<<dim3(88, 8), 256, 0, stream>>>(
      Wq, Wv, W_ih, W_hh, W1, W2, Wk, WqT_h, WvT_h, WihT_h, WhhT_h, W1T_h,
      W2T_h, Wk_h);
  // init: slots from noise + qk/qkb
  slot_update_k<<<SROWS, 1024, 0, stream>>>(
      u_part, S_part, slots, WvT_h, bv, WihT_h, WhhT_h, b_ih, b_hh, g_ff,
      be_ff, W1T_h, b1, W2T_h, b2, g_sl, be_sl, WqT_h, bq, Wk_h, bk, noise,
      slots_mu, slots_ls, slots, qk, qkb, 1, 1);
  xh_prep_k<<<NROWS / 4, 256, 0, stream>>>(inputs, g_in, be_in, xh);
  for (int it = 0; it < 3; ++it) {
    fused_attn_f16_k<<<dim3(NBATCH, NCHK), 256, 0, stream>>>(
        xh, qk, qkb, out_attn, S_part, u_part, (it == 2) ? 1 : 0);
    float* sout = (it == 2) ? out_slots : slots;
    slot_update_k<<<SROWS, 1024, 0, stream>>>(
        u_part, S_part, slots, WvT_h, bv, WihT_h, WhhT_h, b_ih, b_hh, g_ff,
        be_ff, W1T_h, b1, W2T_h, b2, g_sl, be_sl, WqT_h, bq, Wk_h, bk, noise,
        slots_mu, slots_ls, sout, qk, qkb, 0, (it == 2) ? 0 : 1);
  }
}

// Round 9
// 240.553 us; speedup vs baseline: 1.0276x; 1.0276x over previous
//
#include <hip/hip_runtime.h>
#include <hip/hip_fp16.h>
#include <cstdint>
#include <cstddef>

// SlotAttention, round 8.
//  - fused_attn_f16 v2: CH=64, 2 tokens/thread, qk as float4 LDS reads
//    (8 fma per LDS instr), shfl cross-slice reduce, 3 syncs/block.
//  - xh_prep / convert_weights / slot_update structure proven in r6/r7;
//    slot_update back to NCHK=64.

#define NTOK 4096
#define DDIM 256
#define NSLOT 8
#define NBATCH 32
#define CH 64                    // tokens per fused block
#define NCHK 64                  // chunks per batch
#define SROWS (NBATCH * NSLOT)
#define NROWS (NBATCH * NTOK)
#define SCALE 0.0625f
#define LN_EPS_C 1e-5f
#define ATTN_EPS_C 1e-8f

__device__ __forceinline__ void wave_reduce2(float& s, float& ss) {
#pragma unroll
  for (int off = 32; off > 0; off >>= 1) {
    s  += __shfl_down(s, off, 64);
    ss += __shfl_down(ss, off, 64);
  }
}
__device__ __forceinline__ void wave_reduce2_xor(float& s, float& ss) {
#pragma unroll
  for (int off = 32; off > 0; off >>= 1) {
    s  += __shfl_xor(s, off, 64);
    ss += __shfl_xor(ss, off, 64);
  }
}

// transpose 6 weight matrices to fp16; plain-convert Wk to fp16 (r6 proven).
__global__ __launch_bounds__(256) void convert_weights_k(
    const float* __restrict__ Wq, const float* __restrict__ Wv,
    const float* __restrict__ Wih, const float* __restrict__ Whh,
    const float* __restrict__ W1, const float* __restrict__ W2,
    const float* __restrict__ Wk, __half* __restrict__ WqT,
    __half* __restrict__ WvT, __half* __restrict__ WihT,
    __half* __restrict__ WhhT, __half* __restrict__ W1T,
    __half* __restrict__ W2T, __half* __restrict__ Wk_h) {
  __shared__ float tile[32][33];
  int bz = blockIdx.x;
  int tx = threadIdx.x & 31, ty = threadIdx.x >> 5;
  if (bz >= 80) {
    int ro = (bz - 80) * 32, cd = blockIdx.y * 32;
#pragma unroll
    for (int p = 0; p < 32; p += 8)
      Wk_h[(size_t)(ro + ty + p) * DDIM + cd + tx] =
          __float2half(Wk[(size_t)(ro + ty + p) * DDIM + cd + tx]);
    return;
  }
  const float* in; __half* out; int O, bo;
  if (bz < 8)       { in = Wq;  out = WqT;  O = 256; bo = bz; }
  else if (bz < 16) { in = Wv;  out = WvT;  O = 256; bo = bz - 8; }
  else if (bz < 40) { in = Wih; out = WihT; O = 768; bo = bz - 16; }
  else if (bz < 64) { in = Whh; out = WhhT; O = 768; bo = bz - 40; }
  else if (bz < 72) { in = W1;  out = W1T;  O = 256; bo = bz - 64; }
  else              { in = W2;  out = W2T;  O = 256; bo = bz - 72; }
  int ro = bo * 32, cd = blockIdx.y * 32;
#pragma unroll
  for (int p = 0; p < 32; p += 8)
    tile[ty + p][tx] = in[(size_t)(ro + ty + p) * DDIM + cd + tx];
  __syncthreads();
#pragma unroll
  for (int p = 0; p < 32; p += 8)
    out[(size_t)(cd + ty + p) * O + ro + tx] = __float2half(tile[tx][ty + p]);
}

// streaming LN -> fp16. wave per row (64 lanes x float4 = 256 floats).
__global__ __launch_bounds__(256) void xh_prep_k(
    const float* __restrict__ X, const float* __restrict__ g,
    const float* __restrict__ be, __half* __restrict__ xh) {
  int row = blockIdx.x * 4 + (threadIdx.x >> 6);
  int lane = threadIdx.x & 63;
  float4 a = *(const float4*)(X + (size_t)row * DDIM + lane * 4);
  float s = a.x + a.y + a.z + a.w;
  float ss = a.x * a.x + a.y * a.y + a.z * a.z + a.w * a.w;
  wave_reduce2_xor(s, ss);
  float m = s * (1.f / DDIM);
  float rs = rsqrtf(ss * (1.f / DDIM) - m * m + LN_EPS_C);
  float4 gv = *(const float4*)(g + lane * 4);
  float4 bev = *(const float4*)(be + lane * 4);
  union { __half2 h[2]; uint2 u; } pk;
  pk.h[0] = __floats2half2_rn((a.x - m) * rs * gv.x + bev.x,
                              (a.y - m) * rs * gv.y + bev.y);
  pk.h[1] = __floats2half2_rn((a.z - m) * rs * gv.z + bev.z,
                              (a.w - m) * rs * gv.w + bev.w);
  *(uint2*)(xh + (size_t)row * DDIM + lane * 4) = pk.u;
}

// per-iteration token pass v2: block = (b, 64-token chunk c), 256 threads.
//  stage: xh tile -> LDS sx[64][258]; qk -> sq4[8][64] float4; sC0.
//  A (tj=t&31 -> tokens tj,tj+32; qd=t>>5 slice of 32 dims): x in regs,
//    per slot 8 x b128 sq4 reads feeding 8 fma; shfl_down(32) slice-pair
//    combine; write part[4][8][64].
//  B (t<64): dots = sum part + C0; softmax; sa; wave-reduce S.
//  C (thread=dim): u accumulation over 64 tokens -> fp16 store.
__global__ __launch_bounds__(256) void fused_attn_f16_k(
    const __half* __restrict__ xh, const float* __restrict__ qk,
    const float* __restrict__ qkb, float* __restrict__ attn_out,
    float* __restrict__ S_part, __half* __restrict__ u_part, int write_attn) {
  __shared__ __half sx[CH][258];        // 516B rows: 129 dwords = 1 mod 32
  __shared__ float4 sq4[NSLOT][64];     // qk[b] as float4
  __shared__ float part[4][NSLOT][CH];
  __shared__ float sa[NSLOT][CH];
  __shared__ float sC0[NSLOT], sS[NSLOT];
  int b = blockIdx.x, c = blockIdx.y, t = threadIdx.x;
  // stage qk
#pragma unroll
  for (int r2 = 0; r2 < 2; ++r2) {
    int idx = r2 * 256 + t;
    int i = idx >> 6, quad = idx & 63;
    sq4[i][quad] = *(const float4*)(qk + ((size_t)b * NSLOT + i) * DDIM + quad * 4);
  }
  if (t < NSLOT) sC0[t] = qkb[b * NSLOT + t];
  // stage xh tile
  const size_t base = (size_t)b * NTOK + (size_t)c * CH;
#pragma unroll
  for (int it = 0; it < 8; ++it) {
    int e = it * 256 + t;
    int row = e >> 5, c16 = e & 31;
    uint4 v = *(const uint4*)(xh + (base + row) * DDIM + c16 * 8);
    __half2* dst = (__half2*)&sx[row][c16 * 8];
    dst[0] = ((const __half2*)&v)[0];
    dst[1] = ((const __half2*)&v)[1];
    dst[2] = ((const __half2*)&v)[2];
    dst[3] = ((const __half2*)&v)[3];
  }
  __syncthreads();
  // phase A
  {
    int tj = t & 31, qd = t >> 5;   // wave w=t>>6 holds qd {2w, 2w+1}
    float2 xa[16], xb[16];
    const __half2* xra = (const __half2*)&sx[tj][qd * 32];
    const __half2* xrb = (const __half2*)&sx[tj + 32][qd * 32];
#pragma unroll
    for (int d2 = 0; d2 < 16; ++d2) {
      xa[d2] = __half22float2(xra[d2]);
      xb[d2] = __half22float2(xrb[d2]);
    }
    int w = t >> 6;
    bool lo = (t & 63) < 32;
#pragma unroll
    for (int i = 0; i < NSLOT; ++i) {
      float pa = 0.f, pb = 0.f;
#pragma unroll
      for (int d4 = 0; d4 < 8; ++d4) {
        float4 q = sq4[i][qd * 8 + d4];  // 2 addrs/wave -> broadcast
        pa = fmaf(xa[2 * d4].x, q.x, fmaf(xa[2 * d4].y, q.y,
             fmaf(xa[2 * d4 + 1].x, q.z, fmaf(xa[2 * d4 + 1].y, q.w, pa))));
        pb = fmaf(xb[2 * d4].x, q.x, fmaf(xb[2 * d4].y, q.y,
             fmaf(xb[2 * d4 + 1].x, q.z, fmaf(xb[2 * d4 + 1].y, q.w, pb))));
      }
      pa += __shfl_down(pa, 32, 64);   // combine qd pair
      pb += __shfl_down(pb, 32, 64);
      if (lo) { part[w][i][tj] = pa; part[w][i][tj + 32] = pb; }
    }
  }
  __syncthreads();
  // phase B: t<64 = wave 0, token t
  if (t < CH) {
    float dots[NSLOT], mx = -1e30f;
#pragma unroll
    for (int i = 0; i < NSLOT; ++i) {
      dots[i] = part[0][i][t] + part[1][i][t] + part[2][i][t] +
                part[3][i][t] + sC0[i];
      mx = fmaxf(mx, dots[i]);
    }
    float sum = 0.f;
#pragma unroll
    for (int i = 0; i < NSLOT; ++i) { dots[i] = expf(dots[i] - mx); sum += dots[i]; }
    float inv = 1.f / sum;
#pragma unroll
    for (int i = 0; i < NSLOT; ++i) {
      float a = dots[i] * inv;
      if (write_attn)
        attn_out[((size_t)b * NSLOT + i) * NTOK + c * CH + t] = a;
      float ae = a + ATTN_EPS_C;
      sa[i][t] = ae;
      float ps = ae;
#pragma unroll
      for (int off = 32; off > 0; off >>= 1) ps += __shfl_down(ps, off, 64);
      if (t == 0) sS[i] = ps;
    }
  }
  __syncthreads();
  // phase C: thread = dim t
  float acc[NSLOT] = {};
#pragma unroll
  for (int jj = 0; jj < CH; ++jj) {
    float x = __half2float(sx[jj][t]);
#pragma unroll
    for (int i = 0; i < NSLOT; ++i) acc[i] = fmaf(x, sa[i][jj], acc[i]);
  }
  __half* upb = u_part + (((size_t)b * NCHK + c) * NSLOT) * DDIM + t;
#pragma unroll
  for (int i = 0; i < NSLOT; ++i) upb[(size_t)i * DDIM] = __float2half(acc[i]);
  if (t < NSLOT) S_part[((size_t)b * NCHK + c) * NSLOT + t] = sS[t];
}

// slot path, 1024 threads: o = t&255, ks = t>>8. fp16 weights. (r6 proven)
__global__ __launch_bounds__(1024) void slot_update_k(
    const __half* __restrict__ u_part, const float* __restrict__ S_part,
    const float* __restrict__ slots_in, const __half* __restrict__ WvT,
    const float* __restrict__ bv, const __half* __restrict__ WihT,
    const __half* __restrict__ WhhT, const float* __restrict__ b_ih,
    const float* __restrict__ b_hh, const float* __restrict__ g_ff,
    const float* __restrict__ be_ff, const __half* __restrict__ W1T,
    const float* __restrict__ b1, const __half* __restrict__ W2T,
    const float* __restrict__ b2, const float* __restrict__ g_sl,
    const float* __restrict__ be_sl, const __half* __restrict__ WqT,
    const float* __restrict__ bq, const __half* __restrict__ Wk_h,
    const float* __restrict__ bk, const float* __restrict__ noise,
    const float* __restrict__ mu, const float* __restrict__ logsig,
    float* __restrict__ slots_out, float* __restrict__ qk,
    float* __restrict__ qkb_out, int init, int compute_qk) {
  __shared__ float red[4][6][DDIM];
  __shared__ float su[DDIM], sh[DDIM], supd[DDIM], v1[DDIM], v2[DDIM];
  __shared__ float scal[16];
  int r = blockIdx.x, t = threadIdx.x;
  int b = r >> 3, i = r & 7;
  int o = t & 255, ks = t >> 8;
  int lane = t & 63, wid = t >> 6;
  if (init) {
    if (ks == 0) {
      float ns = mu[o] + expf(logsig[o]) * noise[(size_t)r * DDIM + o];
      slots_out[(size_t)r * DDIM + o] = ns;
      v2[o] = ns;
    }
    __syncthreads();
  } else {
    // phase 0: u partials + S reduce + h load
    {
      float up = 0.f;
      const __half* upp =
          u_part + (((size_t)b * NCHK + ks * 16) * NSLOT + i) * DDIM + o;
#pragma unroll
      for (int cc = 0; cc < 16; ++cc)
        up += __half2float(upp[(size_t)cc * (NSLOT * DDIM)]);
      red[ks][0][o] = up;
    }
    if (t < 64) {
      float sp = S_part[((size_t)b * NCHK + t) * NSLOT + i];
#pragma unroll
      for (int off = 32; off > 0; off >>= 1) sp += __shfl_down(sp, off, 64);
      if (t == 0) scal[0] = sp;
    }
    if (ks == 0) sh[o] = slots_in[(size_t)r * DDIM + o];
    __syncthreads();
    if (ks == 0) {
      float invS = 1.f / scal[0];
      su[o] = (red[0][0][o] + red[1][0][o] + red[2][0][o] + red[3][0][o]) * invS;
    }
    __syncthreads();
    // phase 1: Wv
    {
      float p = 0.f;
      const __half* wp = WvT + (size_t)(ks * 64) * DDIM + o;
#pragma unroll 8
      for (int dd = 0; dd < 64; ++dd)
        p = fmaf(su[ks * 64 + dd], __half2float(wp[(size_t)dd * DDIM]), p);
      red[ks][0][o] = p;
    }
    __syncthreads();
    if (ks == 0)
      supd[o] = bv[o] + red[0][0][o] + red[1][0][o] + red[2][0][o] + red[3][0][o];
    __syncthreads();
    // phase 2: GRU (6 matvecs)
    {
      float p0 = 0, p1 = 0, p2 = 0, p3 = 0, p4 = 0, p5 = 0;
      const __half* pi = WihT + (size_t)(ks * 64) * (3 * DDIM) + o;
      const __half* ph = WhhT + (size_t)(ks * 64) * (3 * DDIM) + o;
#pragma unroll 4
      for (int dd = 0; dd < 64; ++dd) {
        float ud = supd[ks * 64 + dd], hd = sh[ks * 64 + dd];
        size_t off = (size_t)dd * (3 * DDIM);
        p0 = fmaf(ud, __half2float(pi[off]), p0);
        p1 = fmaf(ud, __half2float(pi[off + DDIM]), p1);
        p2 = fmaf(ud, __half2float(pi[off + 2 * DDIM]), p2);
        p3 = fmaf(hd, __half2float(ph[off]), p3);
        p4 = fmaf(hd, __half2float(ph[off + DDIM]), p4);
        p5 = fmaf(hd, __half2float(ph[off + 2 * DDIM]), p5);
      }
      red[ks][0][o] = p0; red[ks][1][o] = p1; red[ks][2][o] = p2;
      red[ks][3][o] = p3; red[ks][4][o] = p4; red[ks][5][o] = p5;
    }
    __syncthreads();
    if (ks == 0) {
      float air = b_ih[o] + red[0][0][o] + red[1][0][o] + red[2][0][o] + red[3][0][o];
      float aiz = b_ih[DDIM + o] + red[0][1][o] + red[1][1][o] + red[2][1][o] + red[3][1][o];
      float ain = b_ih[2 * DDIM + o] + red[0][2][o] + red[1][2][o] + red[2][2][o] + red[3][2][o];
      float ahr = b_hh[o] + red[0][3][o] + red[1][3][o] + red[2][3][o] + red[3][3][o];
      float ahz = b_hh[DDIM + o] + red[0][4][o] + red[1][4][o] + red[2][4][o] + red[3][4][o];
      float ahn = b_hh[2 * DDIM + o] + red[0][5][o] + red[1][5][o] + red[2][5][o] + red[3][5][o];
      float rg = 1.f / (1.f + expf(-(air + ahr)));
      float zg = 1.f / (1.f + expf(-(aiz + ahz)));
      float ng = tanhf(ain + rg * ahn);
      float nh = (1.f - zg) * ng + zg * sh[o];
      v1[o] = nh;
      float s2 = nh, ss2 = nh * nh;
      wave_reduce2(s2, ss2);
      if (lane == 0) { scal[wid] = s2; scal[4 + wid] = ss2; }
    }
    __syncthreads();
    if (ks == 0) {
      float sS = scal[0] + scal[1] + scal[2] + scal[3];
      float sQ = scal[4] + scal[5] + scal[6] + scal[7];
      float m = sS * (1.f / DDIM);
      float rs = rsqrtf(sQ * (1.f / DDIM) - m * m + LN_EPS_C);
      v2[o] = (v1[o] - m) * rs * g_ff[o] + be_ff[o];
    }
    __syncthreads();
    // phase 3: W1 + relu
    {
      float p = 0.f;
      const __half* wp = W1T + (size_t)(ks * 64) * DDIM + o;
#pragma unroll 8
      for (int dd = 0; dd < 64; ++dd)
        p = fmaf(v2[ks * 64 + dd], __half2float(wp[(size_t)dd * DDIM]), p);
      red[ks][0][o] = p;
    }
    __syncthreads();
    if (ks == 0)
      su[o] = fmaxf(b1[o] + red[0][0][o] + red[1][0][o] + red[2][0][o] + red[3][0][o], 0.f);
    __syncthreads();
    // phase 4: W2 + residual
    {
      float p = 0.f;
      const __half* wp = W2T + (size_t)(ks * 64) * DDIM + o;
#pragma unroll 8
      for (int dd = 0; dd < 64; ++dd)
        p = fmaf(su[ks * 64 + dd], __half2float(wp[(size_t)dd * DDIM]), p);
      red[ks][0][o] = p;
    }
    __syncthreads();
    if (ks == 0) {
      float out = v1[o] + b2[o] + red[0][0][o] + red[1][0][o] + red[2][0][o] + red[3][0][o];
      slots_out[(size_t)r * DDIM + o] = out;
      v2[o] = out;
    }
    __syncthreads();
  }
  if (!compute_qk) return;
  // qk tail: LN(v2) -> q -> qk, qkb
  if (ks == 0) {
    float x = v2[o];
    float s2 = x, ss2 = x * x;
    wave_reduce2(s2, ss2);
    if (lane == 0) { scal[wid] = s2; scal[4 + wid] = ss2; }
  }
  __syncthreads();
  if (ks == 0) {
    float sS = scal[0] + scal[1] + scal[2] + scal[3];
    float sQ = scal[4] + scal[5] + scal[6] + scal[7];
    float m = sS * (1.f / DDIM);
    float rs = rsqrtf(sQ * (1.f / DDIM) - m * m + LN_EPS_C);
    su[o] = (v2[o] - m) * rs * g_sl[o] + be_sl[o];
  }
  __syncthreads();
  {
    float p = 0.f;
    const __half* wp = WqT + (size_t)(ks * 64) * DDIM + o;
#pragma unroll 8
    for (int dd = 0; dd < 64; ++dd)
      p = fmaf(su[ks * 64 + dd], __half2float(wp[(size_t)dd * DDIM]), p);
    red[ks][0][o] = p;
  }
  __syncthreads();
  if (ks == 0)
    sh[o] = bq[o] + red[0][0][o] + red[1][0][o] + red[2][0][o] + red[3][0][o];
  __syncthreads();
  {
    float p = 0.f;
    const __half* wp = Wk_h + (size_t)(ks * 64) * DDIM + o;
#pragma unroll 8
    for (int dd = 0; dd < 64; ++dd)
      p = fmaf(sh[ks * 64 + dd], __half2float(wp[(size_t)dd * DDIM]), p);
    red[ks][0][o] = p;
  }
  __syncthreads();
  if (ks == 0) {
    float qkv = SCALE * (red[0][0][o] + red[1][0][o] + red[2][0][o] + red[3][0][o]);
    qk[(size_t)r * DDIM + o] = qkv;
    float v0 = sh[o] * bk[o], d1 = 0.f;
    wave_reduce2(v0, d1);
    if (lane == 0) scal[wid] = v0;
  }
  __syncthreads();
  if (t == 0)
    qkb_out[r] = SCALE * (scal[0] + scal[1] + scal[2] + scal[3]);
}

extern "C" void kernel_launch(void* const* d_in, const int* in_sizes, int n_in,
                              void* d_out, int out_size, void* d_ws,
                              size_t ws_size, hipStream_t stream) {
  const float* inputs   = (const float*)d_in[0];
  const float* noise    = (const float*)d_in[1];
  const float* slots_mu = (const float*)d_in[2];
  const float* slots_ls = (const float*)d_in[3];
  const float* Wq   = (const float*)d_in[4];
  const float* bq   = (const float*)d_in[5];
  const float* Wk   = (const float*)d_in[6];
  const float* bk   = (const float*)d_in[7];
  const float* Wv   = (const float*)d_in[8];
  const float* bv   = (const float*)d_in[9];
  const float* W_ih = (const float*)d_in[10];
  const float* W_hh = (const float*)d_in[11];
  const float* b_ih = (const float*)d_in[12];
  const float* b_hh = (const float*)d_in[13];
  const float* W1   = (const float*)d_in[14];
  const float* b1   = (const float*)d_in[15];
  const float* W2   = (const float*)d_in[16];
  const float* b2   = (const float*)d_in[17];
  const float* g_in = (const float*)d_in[18];
  const float* be_in= (const float*)d_in[19];
  const float* g_sl = (const float*)d_in[20];
  const float* be_sl= (const float*)d_in[21];
  const float* g_ff = (const float*)d_in[22];
  const float* be_ff= (const float*)d_in[23];

  float* out_slots = (float*)d_out;                 // [32,8,256]
  float* out_attn  = (float*)d_out + SROWS * DDIM;  // [32,8,4096]

  float* w = (float*)d_ws;
  float* slots = w;  w += SROWS * DDIM;
  float* qk = w;     w += SROWS * DDIM;
  float* qkb = w;    w += SROWS;
  float* S_part = w; w += NBATCH * NCHK * NSLOT;   // 16384
  __half* h = (__half*)w;
  __half* xh = h;     h += (size_t)NROWS * DDIM;                  // 67 MB
  __half* u_part = h; h += (size_t)NBATCH * NCHK * NSLOT * DDIM;  // 8.4 MB
  __half* WqT_h = h;  h += DDIM * DDIM;
  __half* WvT_h = h;  h += DDIM * DDIM;
  __half* WihT_h = h; h += DDIM * 3 * DDIM;
  __half* WhhT_h = h; h += DDIM * 3 * DDIM;
  __half* W1T_h = h;  h += DDIM * DDIM;
  __half* W2T_h = h;  h += DDIM * DDIM;
  __half* Wk_h = h;   h += DDIM * DDIM;
  // total ws ~ 80 MB

  convert_weights_k<<<dim3(88, 8), 256, 0, stream>>>(
      Wq, Wv, W_ih, W_hh, W1, W2, Wk, WqT_h, WvT_h, WihT_h, WhhT_h, W1T_h,
      W2T_h, Wk_h);
  // init: slots from noise + qk/qkb
  slot_update_k<<<SROWS, 1024, 0, stream>>>(
      u_part, S_part, slots, WvT_h, bv, WihT_h, WhhT_h, b_ih, b_hh, g_ff,
      be_ff, W1T_h, b1, W2T_h, b2, g_sl, be_sl, WqT_h, bq, Wk_h, bk, noise,
      slots_mu, slots_ls, slots, qk, qkb, 1, 1);
  xh_prep_k<<<NROWS / 4, 256, 0, stream>>>(inputs, g_in, be_in, xh);
  for (int it = 0; it < 3; ++it) {
    fused_attn_f16_k<<<dim3(NBATCH, NCHK), 256, 0, stream>>>(
        xh, qk, qkb, out_attn, S_part, u_part, (it == 2) ? 1 : 0);
    float* sout = (it == 2) ? out_slots : slots;
    slot_update_k<<<SROWS, 1024, 0, stream>>>(
        u_part, S_part, slots, WvT_h, bv, WihT_h, WhhT_h, b_ih, b_hh, g_ff,
        be_ff, W1T_h, b1, W2T_h, b2, g_sl, be_sl, WqT_h, bq, Wk_h, bk, noise,
        slots_mu, slots_ls, sout, qk, qkb, 0, (it == 2) ? 0 : 1);
  }
}